// Round 11
// baseline (154.061 us; speedup 1.0000x reference)
//
#include <hip/hip_runtime.h>
#include <hip/hip_bf16.h>
#include <math.h>

// OptimizeSNR R11: wave-autonomous LDS-ring streaming MFMA. No barriers.
// Per wave: 16 rows x SPAN positions. Ring = 6 cols x 32 positions x 16 rows
// (bf16, padded strides: col 80B, row 480B -> conflict-free b128).
// Pair i (32 outputs/row): write chunk i+5 (loaded 2 pairs ago), issue load
// chunk i+7, ds_read chunks i..i+4, 20 MFMAs (A and A' Toeplitz), store.
constexpr int Bc = 8, Cc = 128, Lc = 32768, Kc = 129, PAD = Kc / 2;

constexpr int ROWS  = 16;             // channel-rows per wave (MFMA N dim)
constexpr int SPAN  = 512;            // positions per wave
constexpr int PAIRS = SPAN / 32;      // 16
constexpr int WPB   = 2;              // waves per block
constexpr int THREADS = 64 * WPB;     // 128
constexpr int RC    = 6;              // ring columns
constexpr int COLU  = 40;             // col stride in ushorts (80 B)
constexpr int ROWU  = RC * COLU;      // row stride in ushorts (240 u = 480 B)

typedef __attribute__((ext_vector_type(8))) short short8;
typedef __attribute__((ext_vector_type(4))) float floatx4;

__device__ __forceinline__ unsigned short f2bf(float f) {
    return __builtin_bit_cast(unsigned short, __float2bfloat16(f));
}

__device__ __forceinline__ short8 cvt8(const float4& a, const float4& b) {
    __hip_bfloat162 p0 = __float22bfloat162_rn(make_float2(a.x, a.y));
    __hip_bfloat162 p1 = __float22bfloat162_rn(make_float2(a.z, a.w));
    __hip_bfloat162 p2 = __float22bfloat162_rn(make_float2(b.x, b.y));
    __hip_bfloat162 p3 = __float22bfloat162_rn(make_float2(b.z, b.w));
    ushort2 u0, u1, u2, u3;
    __builtin_memcpy(&u0, &p0, 4);
    __builtin_memcpy(&u1, &p1, 4);
    __builtin_memcpy(&u2, &p2, 4);
    __builtin_memcpy(&u3, &p3, 4);
    short8 r;
    r[0] = (short)u0.x; r[1] = (short)u0.y;
    r[2] = (short)u1.x; r[3] = (short)u1.y;
    r[4] = (short)u2.x; r[5] = (short)u2.y;
    r[6] = (short)u3.x; r[7] = (short)u3.y;
    return r;
}

// Per-channel complex scale: sc = nm*cos(atan(a)), ss = nm*sin(atan(a))
__global__ void scale_kernel(const float* __restrict__ wm,
                             const float* __restrict__ wa,
                             float* __restrict__ ws, int C, float batchf) {
    int c = threadIdx.x;
    if (c >= C) return;
    float m = -1e30f;
    for (int i = 0; i < C; ++i) m = fmaxf(m, wm[i]);
    float s = 0.f;
    for (int i = 0; i < C; ++i) s += expf(wm[i] - m);
    float nm = batchf * expf(wm[c] - m) / s;
    float a = wa[c];
    float inv = rsqrtf(1.f + a * a);
    ws[2 * c]     = nm * inv;       // sc
    ws[2 * c + 1] = nm * a * inv;   // ss
}

__global__ __launch_bounds__(THREADS, 3)
void mf_kernel(const float* __restrict__ x,
               const float* __restrict__ kr,
               const float* __restrict__ ki,
               const float* __restrict__ sc_ss,
               float* __restrict__ out, int interleaved) {
    __shared__ __align__(16) unsigned short lx[WPB * ROWS * ROWU];

    const int bx   = blockIdx.x;
    const int bg   = blockIdx.y;
    const int row0 = bg * ROWS;

    const int tid  = threadIdx.x;
    const int lane = tid & 63;
    const int wv   = tid >> 6;         // wave 0..1
    const int fh   = lane >> 4;        // 0..3 (MFMA k-half)
    const int fn   = lane & 15;        // 0..15 (MFMA n = row)
    const int srw  = lane >> 2;        // staging row 0..15
    const int sq   = lane & 3;         // staging quad 0..3

    const int S = (bx * WPB + wv) * SPAN;   // this wave's span start
    unsigned short* lw = &lx[wv * (ROWS * ROWU)];

    // ---- A fragments. A_d[m][kl] = k[32d+kl-m]; A'_d[m][kl] = k[32d+kl-16-m].
    short8 ar[5], ai[5], arp[5], aip[5];
    #pragma unroll
    for (int d = 0; d < 5; ++d) {
        #pragma unroll
        for (int e = 0; e < 8; ++e) {
            const int kl  = 8 * fh + e;
            const int idx = 32 * d + kl - fn;
            const int idp = idx - 16;
            bool ok  = (idx >= 0) && (idx < Kc);
            bool okp = (idp >= 0) && (idp < Kc);
            ar[d][e]  = (short)f2bf(ok  ? kr[idx] : 0.f);
            ai[d][e]  = (short)f2bf(ok  ? ki[idx] : 0.f);
            arp[d][e] = (short)f2bf(okp ? kr[idp] : 0.f);
            aip[d][e] = (short)f2bf(okp ? ki[idp] : 0.f);
        }
    }

    const int ch = (row0 + fn) & (Cc - 1);
    const float scv = sc_ss[2 * ch];
    const float ssv = sc_ss[2 * ch + 1];

    const float* __restrict__ xsrow = x + (size_t)(row0 + srw) * Lc;
    float* __restrict__ orow = out + (size_t)(row0 + fn) * Lc;

    const bool interior = (S >= 64) && (S + SPAN + 64 <= Lc);

    // chunk c covers positions [S-64+32c, S-64+32c+32); lane loads 8 floats.
    auto LOADC = [&](int c, float4& a, float4& b) {
        const int g0 = S - 64 + 32 * c + 8 * sq;
        if (interior) {
            a = *reinterpret_cast<const float4*>(xsrow + g0);
            b = *reinterpret_cast<const float4*>(xsrow + g0 + 4);
        } else {
            a.x = (g0 + 0 >= 0 && g0 + 0 < Lc) ? xsrow[g0 + 0] : 0.f;
            a.y = (g0 + 1 >= 0 && g0 + 1 < Lc) ? xsrow[g0 + 1] : 0.f;
            a.z = (g0 + 2 >= 0 && g0 + 2 < Lc) ? xsrow[g0 + 2] : 0.f;
            a.w = (g0 + 3 >= 0 && g0 + 3 < Lc) ? xsrow[g0 + 3] : 0.f;
            b.x = (g0 + 4 >= 0 && g0 + 4 < Lc) ? xsrow[g0 + 4] : 0.f;
            b.y = (g0 + 5 >= 0 && g0 + 5 < Lc) ? xsrow[g0 + 5] : 0.f;
            b.z = (g0 + 6 >= 0 && g0 + 6 < Lc) ? xsrow[g0 + 6] : 0.f;
            b.w = (g0 + 7 >= 0 && g0 + 7 < Lc) ? xsrow[g0 + 7] : 0.f;
        }
    };
    auto WRITEC = [&](int c, const float4& a, const float4& b) {
        short8 h = cvt8(a, b);
        *reinterpret_cast<short8*>(&lw[srw * ROWU + (c % RC) * COLU + sq * 8]) = h;
    };

    // ---- prologue: fill ring chunks 0..4; leave chunk 5 in B, 6 in A ----
    float4 a0, b0, a1, b1;
    LOADC(0, a0, b0); LOADC(1, a1, b1);
    WRITEC(0, a0, b0); LOADC(2, a0, b0);
    WRITEC(1, a1, b1); LOADC(3, a1, b1);
    WRITEC(2, a0, b0); LOADC(4, a0, b0);
    WRITEC(3, a1, b1); LOADC(5, a1, b1);   // chunk 5 -> buf B
    WRITEC(4, a0, b0); LOADC(6, a0, b0);   // chunk 6 -> buf A

    // ---- main: pair i covers outputs q=S+32i .. +32 via chunks i..i+4 ----
    #pragma unroll
    for (int i = 0; i < PAIRS; ++i) {
        // write chunk i+5 (even i: from B, odd i: from A), then refill buf
        if ((i & 1) == 0) {
            WRITEC(i + 5, a1, b1);
            if (i + 7 <= PAIRS + 3) LOADC(i + 7, a1, b1);
        } else {
            WRITEC(i + 5, a0, b0);
            if (i + 7 <= PAIRS + 3) LOADC(i + 7, a0, b0);
        }

        floatx4 c0r = {0.f, 0.f, 0.f, 0.f}, c0i = {0.f, 0.f, 0.f, 0.f};
        floatx4 c1r = {0.f, 0.f, 0.f, 0.f}, c1i = {0.f, 0.f, 0.f, 0.f};
        #pragma unroll
        for (int d = 0; d < 5; ++d) {
            const short8 w = *reinterpret_cast<const short8*>(
                &lw[fn * ROWU + ((i + d) % RC) * COLU + fh * 8]);
            c0r = __builtin_amdgcn_mfma_f32_16x16x32_bf16(ar[d],  w, c0r, 0, 0, 0);
            c0i = __builtin_amdgcn_mfma_f32_16x16x32_bf16(ai[d],  w, c0i, 0, 0, 0);
            c1r = __builtin_amdgcn_mfma_f32_16x16x32_bf16(arp[d], w, c1r, 0, 0, 0);
            c1i = __builtin_amdgcn_mfma_f32_16x16x32_bf16(aip[d], w, c1i, 0, 0, 0);
        }

        const int q = S + 32 * i;
        if (!interleaved) {
            float4 o0, o1;
            o0.x = scv * c0r[0] - ssv * c0i[0];
            o0.y = scv * c0r[1] - ssv * c0i[1];
            o0.z = scv * c0r[2] - ssv * c0i[2];
            o0.w = scv * c0r[3] - ssv * c0i[3];
            o1.x = scv * c1r[0] - ssv * c1i[0];
            o1.y = scv * c1r[1] - ssv * c1i[1];
            o1.z = scv * c1r[2] - ssv * c1i[2];
            o1.w = scv * c1r[3] - ssv * c1i[3];
            *reinterpret_cast<float4*>(orow + q + 4 * fh)      = o0;
            *reinterpret_cast<float4*>(orow + q + 16 + 4 * fh) = o1;
        } else {
            float2* oa = reinterpret_cast<float2*>(out) +
                         ((size_t)(row0 + fn) * Lc + q + 4 * fh);
            float2* ob = oa + 16;
            #pragma unroll
            for (int r = 0; r < 4; ++r) {
                oa[r] = make_float2(scv * c0r[r] - ssv * c0i[r],
                                    -scv * c0i[r] - ssv * c0r[r]);
                ob[r] = make_float2(scv * c1r[r] - ssv * c1i[r],
                                    -scv * c1i[r] - ssv * c1r[r]);
            }
        }
    }
}

extern "C" void kernel_launch(void* const* d_in, const int* in_sizes, int n_in,
                              void* d_out, int out_size, void* d_ws, size_t ws_size,
                              hipStream_t stream) {
    const float* x  = (const float*)d_in[0];
    const float* wm = (const float*)d_in[1];
    const float* wa = (const float*)d_in[2];
    const float* kr = (const float*)d_in[3];
    const float* ki = (const float*)d_in[4];
    float* out = (float*)d_out;
    float* ws  = (float*)d_ws;

    const int C = in_sizes[1];  // 128
    const long long N = (long long)Bc * Cc * Lc;
    const int interleaved = (out_size == 2 * N) ? 1 : 0;

    hipLaunchKernelGGL(scale_kernel, dim3(1), dim3(C), 0, stream,
                       wm, wa, ws, C, (float)Bc);

    dim3 grid(Lc / (SPAN * WPB), (Bc * Cc) / ROWS);   // 32 x 64 = 2048 blocks
    hipLaunchKernelGGL(mf_kernel, grid, dim3(THREADS), 0, stream,
                       x, kr, ki, ws, out, interleaved);
}

// Round 12
// 116.086 us; speedup vs baseline: 1.3271x; 1.3271x over previous
//
#include <hip/hip_runtime.h>
#include <hip/hip_bf16.h>
#include <math.h>

// OptimizeSNR R12: fp32-in-LDS via global_load_lds DMA (issue-only staging),
// bf16 conversion at fragment-read time, MFMA Toeplitz compute.
//   out[n, t+m] = sum_p A[m,p] * B[p,n],  A[m,p]=k[p-m] (VGPRs)
//   B[p,n] = x_rowN[s0+p]  (fp32 in LDS, cvt_pk at read)
constexpr int Bc = 8, Cc = 128, Lc = 32768, Kc = 129, PAD = Kc / 2;

constexpr int ROWS   = 16;             // channel-rows per block (MFMA N dim)
constexpr int MLEN   = 512;            // output positions per block per row
constexpr int PSPAN  = MLEN + 144;     // 656 dwords staged per row
constexpr int PSTRD  = 660;            // row stride in dwords (2640 B; bank stride 20 -> 2-way free)
constexpr int LDS_DW = ROWS * PSTRD;   // 10560 dwords = 42240 B
constexpr int NDMA   = (LDS_DW * 4 + 1023) / 1024;  // 42 x 1KB wave-instructions
constexpr int LDS_PAD_DW = NDMA * 256; // 10752 dwords = 43008 B (768 B pad tail, never read)
constexpr int THREADS= 256;
constexpr int NTILES = MLEN / 16;      // 32
constexpr int TPW    = NTILES / 4;     // 8 tiles per wave

typedef __attribute__((ext_vector_type(8))) short short8;
typedef __attribute__((ext_vector_type(4))) float floatx4;

__device__ __forceinline__ unsigned short f2bf(float f) {
    return __builtin_bit_cast(unsigned short, __float2bfloat16(f));
}

__device__ __forceinline__ short8 cvt8(const float4& a, const float4& b) {
    __hip_bfloat162 p0 = __float22bfloat162_rn(make_float2(a.x, a.y));
    __hip_bfloat162 p1 = __float22bfloat162_rn(make_float2(a.z, a.w));
    __hip_bfloat162 p2 = __float22bfloat162_rn(make_float2(b.x, b.y));
    __hip_bfloat162 p3 = __float22bfloat162_rn(make_float2(b.z, b.w));
    ushort2 u0, u1, u2, u3;
    __builtin_memcpy(&u0, &p0, 4);
    __builtin_memcpy(&u1, &p1, 4);
    __builtin_memcpy(&u2, &p2, 4);
    __builtin_memcpy(&u3, &p3, 4);
    short8 r;
    r[0] = (short)u0.x; r[1] = (short)u0.y;
    r[2] = (short)u1.x; r[3] = (short)u1.y;
    r[4] = (short)u2.x; r[5] = (short)u2.y;
    r[6] = (short)u3.x; r[7] = (short)u3.y;
    return r;
}

__device__ __forceinline__ void gload_lds16(const float* g, void* l) {
    auto gp = (const __attribute__((address_space(1))) void*)g;
    auto lp = (__attribute__((address_space(3))) void*)l;
    __builtin_amdgcn_global_load_lds(gp, lp, 16, 0, 0);
}

// Per-channel complex scale: sc = nm*cos(atan(a)), ss = nm*sin(atan(a))
__global__ void scale_kernel(const float* __restrict__ wm,
                             const float* __restrict__ wa,
                             float* __restrict__ ws, int C, float batchf) {
    int c = threadIdx.x;
    if (c >= C) return;
    float m = -1e30f;
    for (int i = 0; i < C; ++i) m = fmaxf(m, wm[i]);
    float s = 0.f;
    for (int i = 0; i < C; ++i) s += expf(wm[i] - m);
    float nm = batchf * expf(wm[c] - m) / s;
    float a = wa[c];
    float inv = rsqrtf(1.f + a * a);
    ws[2 * c]     = nm * inv;       // sc
    ws[2 * c + 1] = nm * a * inv;   // ss
}

__global__ __launch_bounds__(THREADS, 3)
void mf_kernel(const float* __restrict__ x,
               const float* __restrict__ kr,
               const float* __restrict__ ki,
               const float* __restrict__ sc_ss,
               float* __restrict__ out, int interleaved) {
    __shared__ __align__(16) float lf[LDS_PAD_DW];

    const int bx   = blockIdx.x;       // position tile (64)
    const int bg   = blockIdx.y;       // row group (64)
    const int row0 = bg * ROWS;
    const int P0   = bx * MLEN;
    const int s0   = P0 - PAD;

    const int tid  = threadIdx.x;
    const int lane = tid & 63;
    const int fh   = lane >> 4;        // 0..3
    const int fn   = lane & 15;        // 0..15
    const int wv   = tid >> 6;         // wave 0..3

    const float* __restrict__ xbase = x + (size_t)row0 * Lc;
    const bool interior = (s0 >= 0) && (s0 + PSPAN + 4 <= Lc);

    if (interior) {
        // ---- DMA staging: issue-only, zero VGPR round-trip. ----
        // LDS linear layout = row-major [16][PSTRD] fp32. Instruction t writes
        // LDS bytes [1024t, 1024t+1024); lane L supplies 16 B from the matching
        // global row/col. Tail (t=41 upper lanes) lands in the pad -> clamp addr.
        #pragma unroll
        for (int tt = 0; tt < 11; ++tt) {
            const int t = wv * 11 + tt;
            if (t < NDMA) {
                const unsigned D = 256u * t + 4u * lane;   // dword index in LDS
                unsigned row = D / PSTRD;
                unsigned col = D - row * PSTRD;
                if (row >= ROWS) { row = 0; col = 0; }     // pad tail: safe addr
                const float* g = xbase + (size_t)row * Lc + (s0 + (int)col);
                gload_lds16(g, (char*)lf + 1024 * t);
            }
        }
    }

    // ---- A fragments under the DMA shadow: A_d[m][kl]=k[32d+kl-m] ----
    short8 ar[5], ai[5];
    #pragma unroll
    for (int d = 0; d < 5; ++d) {
        #pragma unroll
        for (int e = 0; e < 8; ++e) {
            int idx = 32 * d + 8 * fh + e - fn;
            bool ok = (idx >= 0) && (idx < Kc);
            ar[d][e] = (short)f2bf(ok ? kr[idx] : 0.f);
            ai[d][e] = (short)f2bf(ok ? ki[idx] : 0.f);
        }
    }

    if (!interior) {
        // ---- edge blocks (bx==0 / bx==63): guarded reg staging ----
        const int srow = tid >> 4;     // 16 threads per row
        const int scol = tid & 15;
        const float* __restrict__ xr = x + (size_t)(row0 + srow) * Lc;
        float* lrow = &lf[srow * PSTRD];
        #pragma unroll
        for (int i = 0; i < 11; ++i) {
            const int i4 = scol + 16 * i;
            if (i4 < PSTRD / 4) {
                const int g = s0 + 4 * i4;
                float4 v;
                v.x = (g + 0 >= 0 && g + 0 < Lc) ? xr[g + 0] : 0.f;
                v.y = (g + 1 >= 0 && g + 1 < Lc) ? xr[g + 1] : 0.f;
                v.z = (g + 2 >= 0 && g + 2 < Lc) ? xr[g + 2] : 0.f;
                v.w = (g + 3 >= 0 && g + 3 < Lc) ? xr[g + 3] : 0.f;
                *reinterpret_cast<float4*>(&lrow[4 * i4]) = v;
            }
        }
    }
    __syncthreads();   // compiler emits vmcnt(0) drain -> DMA data landed

    // ---- per-lane channel scale (lane owns channel-row row0+fn) ----
    const int ch = (row0 + fn) & (Cc - 1);
    const float scv = sc_ss[2 * ch];
    const float ssv = sc_ss[2 * ch + 1];

    #pragma unroll
    for (int jj = 0; jj < TPW; ++jj) {
        const int j  = wv * TPW + jj;
        const int pb = 16 * j;
        const int base = fn * PSTRD + pb + 8 * fh;
        floatx4 cr = {0.f, 0.f, 0.f, 0.f};
        floatx4 cim = {0.f, 0.f, 0.f, 0.f};
        #pragma unroll
        for (int d = 0; d < 5; ++d) {
            float4 fa = *reinterpret_cast<const float4*>(&lf[base + 32 * d]);
            float4 fb = *reinterpret_cast<const float4*>(&lf[base + 32 * d + 4]);
            short8 b = cvt8(fa, fb);
            cr  = __builtin_amdgcn_mfma_f32_16x16x32_bf16(ar[d], b, cr, 0, 0, 0);
            cim = __builtin_amdgcn_mfma_f32_16x16x32_bf16(ai[d], b, cim, 0, 0, 0);
        }
        // D layout: lane holds D[m = 4*fh + r][n = fn]
        const size_t obase = (size_t)(row0 + fn) * Lc + P0 + pb + 4 * fh;
        if (!interleaved) {
            float4 o;
            o.x = scv * cr[0] - ssv * cim[0];
            o.y = scv * cr[1] - ssv * cim[1];
            o.z = scv * cr[2] - ssv * cim[2];
            o.w = scv * cr[3] - ssv * cim[3];
            *reinterpret_cast<float4*>(out + obase) = o;
        } else {
            float2* o2 = reinterpret_cast<float2*>(out) + obase;
            #pragma unroll
            for (int r = 0; r < 4; ++r) {
                o2[r] = make_float2(scv * cr[r] - ssv * cim[r],
                                    -scv * cim[r] - ssv * cr[r]);
            }
        }
    }
}

extern "C" void kernel_launch(void* const* d_in, const int* in_sizes, int n_in,
                              void* d_out, int out_size, void* d_ws, size_t ws_size,
                              hipStream_t stream) {
    const float* x  = (const float*)d_in[0];
    const float* wm = (const float*)d_in[1];
    const float* wa = (const float*)d_in[2];
    const float* kr = (const float*)d_in[3];
    const float* ki = (const float*)d_in[4];
    float* out = (float*)d_out;
    float* ws  = (float*)d_ws;

    const int C = in_sizes[1];  // 128
    const long long N = (long long)Bc * Cc * Lc;
    const int interleaved = (out_size == 2 * N) ? 1 : 0;

    hipLaunchKernelGGL(scale_kernel, dim3(1), dim3(C), 0, stream,
                       wm, wa, ws, C, (float)Bc);

    dim3 grid(Lc / MLEN, (Bc * Cc) / ROWS);   // 64 x 64 = 4096 blocks
    hipLaunchKernelGGL(mf_kernel, grid, dim3(THREADS), 0, stream,
                       x, kr, ki, ws, out, interleaved);
}

// Round 13
// 77.663 us; speedup vs baseline: 1.9837x; 1.4947x over previous
//
#include <hip/hip_runtime.h>
#include <hip/hip_bf16.h>
#include <math.h>

// OptimizeSNR R13: 3-stage per-block pipeline.
//   DMA (issue-only, fp32 -> LDS) | conv (LDS fp32 -> LDS bf16, per-wave rows)
//   | compute (ds_read_b128 bf16 + MFMA Toeplitz, zero cvt on critical path).
// Single fp32 buffer (nothing reads fp32 during compute), separate bf16 buffer.
constexpr int Bc = 8, Cc = 128, Lc = 32768, Kc = 129, PAD = Kc / 2;

constexpr int ROWS   = 16;          // channel-rows per block
constexpr int MLEN   = 512;         // positions per chunk
constexpr int NCH    = 4;           // chunks per block
constexpr int STG    = 768;         // staged dwords per row (3x256, covers 656 span)
constexpr int F32STR = 772;         // fp32 row stride dwords (3088B; (r+lane)%8 balanced)
constexpr int BF_STR = 776;         // bf16 row stride shorts (1552B; (97fn+fh)%8 balanced)
constexpr int THREADS= 512;         // 8 waves; wave wv owns rows 2wv, 2wv+1
constexpr int TPW    = 4;           // tiles per wave (32 tiles per chunk)

typedef __attribute__((ext_vector_type(8))) short short8;
typedef __attribute__((ext_vector_type(4))) float floatx4;

__device__ __forceinline__ unsigned short f2bf(float f) {
    return __builtin_bit_cast(unsigned short, __float2bfloat16(f));
}

__device__ __forceinline__ void gload_lds16(const float* g, void* l) {
    auto gp = (const __attribute__((address_space(1))) void*)g;
    auto lp = (__attribute__((address_space(3))) void*)l;
    __builtin_amdgcn_global_load_lds(gp, lp, 16, 0, 0);
}

// Per-channel complex scale: sc = nm*cos(atan(a)), ss = nm*sin(atan(a))
__global__ void scale_kernel(const float* __restrict__ wm,
                             const float* __restrict__ wa,
                             float* __restrict__ ws, int C, float batchf) {
    int c = threadIdx.x;
    if (c >= C) return;
    float m = -1e30f;
    for (int i = 0; i < C; ++i) m = fmaxf(m, wm[i]);
    float s = 0.f;
    for (int i = 0; i < C; ++i) s += expf(wm[i] - m);
    float nm = batchf * expf(wm[c] - m) / s;
    float a = wa[c];
    float inv = rsqrtf(1.f + a * a);
    ws[2 * c]     = nm * inv;       // sc
    ws[2 * c + 1] = nm * a * inv;   // ss
}

__global__ __launch_bounds__(THREADS, 4)   // 2 blocks/CU (LDS 74KB), VGPR<=128
void mf_kernel(const float* __restrict__ x,
               const float* __restrict__ kr,
               const float* __restrict__ ki,
               const float* __restrict__ sc_ss,
               float* __restrict__ out, int interleaved) {
    __shared__ __align__(16) float          lf[ROWS * F32STR];  // 49408 B
    __shared__ __align__(16) unsigned short lb[ROWS * BF_STR];  // 24832 B

    const int bx   = blockIdx.x;       // chunk group (16)
    const int bg   = blockIdx.y;       // row group (64)
    const int row0 = bg * ROWS;

    const int tid  = threadIdx.x;
    const int lane = tid & 63;
    const int wv   = tid >> 6;         // 0..7
    const int fh   = lane >> 4;        // 0..3
    const int fn   = lane & 15;        // 0..15

    // ---- A fragments: A_d[m][kl] = k[32d + kl - m]; lane holds m=fn, kl=8*fh+e ----
    short8 ar[5], ai[5];
    #pragma unroll
    for (int d = 0; d < 5; ++d) {
        #pragma unroll
        for (int e = 0; e < 8; ++e) {
            int idx = 32 * d + 8 * fh + e - fn;
            bool ok = (idx >= 0) && (idx < Kc);
            ar[d][e] = (short)f2bf(ok ? kr[idx] : 0.f);
            ai[d][e] = (short)f2bf(ok ? ki[idx] : 0.f);
        }
    }
    const int ch = (row0 + fn) & (Cc - 1);
    const float scv = sc_ss[2 * ch];
    const float ssv = sc_ss[2 * ch + 1];

    auto s0_of = [&](int c) { return (bx * NCH + c) * MLEN - 2 * PAD + 64; };
    // s0 = P0 - 64 with P0 = (bx*NCH+c)*MLEN; (writing it explicitly:)
    // positions staged: [s0, s0+768)

    auto is_edge = [&](int c) {
        const int s0 = (bx * NCH + c) * MLEN - 64;
        return (s0 < 0) || (s0 + STG > Lc);
    };

    // DMA issue-only staging: wave wv stages rows 2wv, 2wv+1, parts p=0..2.
    auto DMA_STAGE = [&](int c) {
        const int s0 = (bx * NCH + c) * MLEN - 64;
        #pragma unroll
        for (int rr = 0; rr < 2; ++rr) {
            const int r = 2 * wv + rr;
            const float* xr = x + (size_t)(row0 + r) * Lc + s0 + 4 * lane;
            #pragma unroll
            for (int p = 0; p < 3; ++p) {
                gload_lds16(xr + 256 * p, (char*)lf + 3088 * r + 1024 * p);
            }
        }
    };

    // Edge staging: guarded scalar loads, normal ds writes (needs barrier after).
    auto EDGE_STAGE = [&](int c) {
        const int s0 = (bx * NCH + c) * MLEN - 64;
        const int r = tid >> 5;        // 32 threads per row
        const int scol = tid & 31;
        const float* xr = x + (size_t)(row0 + r) * Lc;
        #pragma unroll
        for (int i = 0; i < 6; ++i) {
            const int c4 = 4 * (scol + 32 * i);   // dword col 0..764
            const int g = s0 + c4;
            float4 v;
            v.x = (g + 0 >= 0 && g + 0 < Lc) ? xr[g + 0] : 0.f;
            v.y = (g + 1 >= 0 && g + 1 < Lc) ? xr[g + 1] : 0.f;
            v.z = (g + 2 >= 0 && g + 2 < Lc) ? xr[g + 2] : 0.f;
            v.w = (g + 3 >= 0 && g + 3 < Lc) ? xr[g + 3] : 0.f;
            *reinterpret_cast<float4*>(&lf[F32STR * r + c4]) = v;
        }
    };

    // conv: wave wv converts its rows fp32 -> bf16.
    auto CONV = [&]() {
        #pragma unroll
        for (int rr = 0; rr < 2; ++rr) {
            const int r = 2 * wv + rr;
            #pragma unroll
            for (int p = 0; p < 3; ++p) {
                const int dw = 256 * p + 4 * lane;
                float4 v = *reinterpret_cast<const float4*>(&lf[F32STR * r + dw]);
                __hip_bfloat162 p0 = __float22bfloat162_rn(make_float2(v.x, v.y));
                __hip_bfloat162 p1 = __float22bfloat162_rn(make_float2(v.z, v.w));
                ushort2 u0, u1;
                __builtin_memcpy(&u0, &p0, 4);
                __builtin_memcpy(&u1, &p1, 4);
                ushort4 h; h.x = u0.x; h.y = u0.y; h.z = u1.x; h.w = u1.y;
                *reinterpret_cast<ushort4*>(&lb[BF_STR * r + dw]) = h;
            }
        }
    };

    auto COMPUTE = [&](int c) {
        const int P0 = (bx * NCH + c) * MLEN;
        #pragma unroll
        for (int jj = 0; jj < TPW; ++jj) {
            const int j = wv * TPW + jj;          // tile 0..31
            floatx4 cr = {0.f, 0.f, 0.f, 0.f};
            floatx4 cim = {0.f, 0.f, 0.f, 0.f};
            const unsigned short* lp = &lb[BF_STR * fn + 16 * j + 8 * fh];
            #pragma unroll
            for (int d = 0; d < 5; ++d) {
                short8 b = *reinterpret_cast<const short8*>(lp + 32 * d);
                cr  = __builtin_amdgcn_mfma_f32_16x16x32_bf16(ar[d], b, cr, 0, 0, 0);
                cim = __builtin_amdgcn_mfma_f32_16x16x32_bf16(ai[d], b, cim, 0, 0, 0);
            }
            const size_t obase = (size_t)(row0 + fn) * Lc + P0 + 16 * j + 4 * fh;
            if (!interleaved) {
                float4 o;
                o.x = scv * cr[0] - ssv * cim[0];
                o.y = scv * cr[1] - ssv * cim[1];
                o.z = scv * cr[2] - ssv * cim[2];
                o.w = scv * cr[3] - ssv * cim[3];
                *reinterpret_cast<float4*>(out + obase) = o;
            } else {
                float2* o2 = reinterpret_cast<float2*>(out) + obase;
                #pragma unroll
                for (int r = 0; r < 4; ++r) {
                    o2[r] = make_float2(scv * cr[r] - ssv * cim[r],
                                        -scv * cim[r] - ssv * cr[r]);
                }
            }
        }
    };

    // ---- prologue ----
    if (!is_edge(0)) DMA_STAGE(0);

    #pragma unroll 1
    for (int c = 0; c < NCH; ++c) {
        if (is_edge(c)) {
            EDGE_STAGE(c);
            __syncthreads();                        // fp32 ready (cross-wave writes)
        } else {
            asm volatile("s_waitcnt vmcnt(0)" ::: "memory");  // own DMAs landed
            __builtin_amdgcn_sched_barrier(0);
        }
        CONV();
        __syncthreads();                            // bf16 ready for all rows
        if (c + 1 < NCH && !is_edge(c + 1)) DMA_STAGE(c + 1);
        COMPUTE(c);
        __syncthreads();                            // bf16 free for next conv
    }
}

extern "C" void kernel_launch(void* const* d_in, const int* in_sizes, int n_in,
                              void* d_out, int out_size, void* d_ws, size_t ws_size,
                              hipStream_t stream) {
    const float* x  = (const float*)d_in[0];
    const float* wm = (const float*)d_in[1];
    const float* wa = (const float*)d_in[2];
    const float* kr = (const float*)d_in[3];
    const float* ki = (const float*)d_in[4];
    float* out = (float*)d_out;
    float* ws  = (float*)d_ws;

    const int C = in_sizes[1];  // 128
    const long long N = (long long)Bc * Cc * Lc;
    const int interleaved = (out_size == 2 * N) ? 1 : 0;

    hipLaunchKernelGGL(scale_kernel, dim3(1), dim3(C), 0, stream,
                       wm, wa, ws, C, (float)Bc);

    dim3 grid(Lc / (MLEN * NCH), (Bc * Cc) / ROWS);   // 16 x 64 = 1024 blocks
    hipLaunchKernelGGL(mf_kernel, grid, dim3(THREADS), 0, stream,
                       x, kr, ki, ws, out, interleaved);
}

// Round 14
// 74.745 us; speedup vs baseline: 2.0612x; 1.0390x over previous
//
#include <hip/hip_runtime.h>
#include <hip/hip_bf16.h>
#include <math.h>

// OptimizeSNR R14: depth-2 counted-vmcnt DMA pipeline.
//   Per block: 16 rows x 16 chunks of 256 positions.
//   fp32 staging: double-buffered, WAVE-PRIVATE rows (2/wave) via
//   global_load_lds (issue-only). bf16 buffer: single, rebuilt per chunk.
//   Chunk c: vmcnt(counted) -> CONV -> lgkm -> DMA(c+2) -> s_barrier ->
//            COMPUTE(c) -> lgkm -> s_barrier.   (raw barriers: no vmcnt drain)
constexpr int Bc = 8, Cc = 128, Lc = 32768, Kc = 129, PAD = Kc / 2;

constexpr int ROWS   = 16;
constexpr int MLEN   = 256;         // positions per chunk
constexpr int NCH    = 16;          // chunks per block
constexpr int NEED_DW= 400;         // used span per row (256 + 144)
constexpr int F32STR = 516;         // fp32 row stride (dwords); staged 512 dw
constexpr int BFSTR  = 408;         // bf16 row stride (shorts); 816B = 16*51 -> b128 conflict-free
constexpr int THREADS= 512;         // 8 waves; wave wv owns rows 2wv, 2wv+1

typedef __attribute__((ext_vector_type(8))) short short8;
typedef __attribute__((ext_vector_type(4))) float floatx4;

__device__ __forceinline__ unsigned short f2bf(float f) {
    return __builtin_bit_cast(unsigned short, __float2bfloat16(f));
}

__device__ __forceinline__ void gload_lds16(const float* g, void* l) {
    auto gp = (const __attribute__((address_space(1))) void*)g;
    auto lp = (__attribute__((address_space(3))) void*)l;
    __builtin_amdgcn_global_load_lds(gp, lp, 16, 0, 0);
}

// Per-channel complex scale: sc = nm*cos(atan(a)), ss = nm*sin(atan(a))
__global__ void scale_kernel(const float* __restrict__ wm,
                             const float* __restrict__ wa,
                             float* __restrict__ ws, int C, float batchf) {
    int c = threadIdx.x;
    if (c >= C) return;
    float m = -1e30f;
    for (int i = 0; i < C; ++i) m = fmaxf(m, wm[i]);
    float s = 0.f;
    for (int i = 0; i < C; ++i) s += expf(wm[i] - m);
    float nm = batchf * expf(wm[c] - m) / s;
    float a = wa[c];
    float inv = rsqrtf(1.f + a * a);
    ws[2 * c]     = nm * inv;       // sc
    ws[2 * c + 1] = nm * a * inv;   // ss
}

__global__ __launch_bounds__(THREADS, 4)   // 2 blocks/CU (LDS 79.1 KB)
void mf_kernel(const float* __restrict__ x,
               const float* __restrict__ kr,
               const float* __restrict__ ki,
               const float* __restrict__ sc_ss,
               float* __restrict__ out, int interleaved) {
    __shared__ __align__(16) float          lf[2][ROWS * F32STR];  // 66048 B
    __shared__ __align__(16) unsigned short lb[ROWS * BFSTR];      // 13056 B

    const int bx   = blockIdx.x;       // 8 chunk-groups
    const int bg   = blockIdx.y;       // 64 row groups
    const int row0 = bg * ROWS;

    const int tid  = threadIdx.x;
    const int lane = tid & 63;
    const int wv   = tid >> 6;         // 0..7
    const int fh   = lane >> 4;        // 0..3
    const int fn   = lane & 15;        // 0..15

    // ---- A fragments: A_d[m][kl] = k[32d + kl - m]; lane holds m=fn, kl=8*fh+e ----
    short8 ar[5], ai[5];
    #pragma unroll
    for (int d = 0; d < 5; ++d) {
        #pragma unroll
        for (int e = 0; e < 8; ++e) {
            int idx = 32 * d + 8 * fh + e - fn;
            bool ok = (idx >= 0) && (idx < Kc);
            ar[d][e] = (short)f2bf(ok ? kr[idx] : 0.f);
            ai[d][e] = (short)f2bf(ok ? ki[idx] : 0.f);
        }
    }
    const int ch = (row0 + fn) & (Cc - 1);
    const float scv = sc_ss[2 * ch];
    const float ssv = sc_ss[2 * ch + 1];

    // ---- DMA: issue-only, wave-private rows, 2 x 1KB per row ----
    auto DMA = [&](int pc, int buf) {
        const int s0 = pc * MLEN - PAD;
        #pragma unroll
        for (int rr = 0; rr < 2; ++rr) {
            const int r = 2 * wv + rr;
            const float* g = x + (size_t)(row0 + r) * Lc + s0 + 4 * lane;
            char* l = (char*)&lf[buf][r * F32STR];
            gload_lds16(g, l);
            gload_lds16(g + 256, l + 1024);
        }
    };

    // ---- edge staging (pc 0 / 127): guarded reg loads, wave-private rows ----
    auto EDGE = [&](int pc, int buf) {
        const int s0 = pc * MLEN - PAD;
        const int r  = tid >> 5;       // rows 2wv, 2wv+1 for this wave
        const int sc = tid & 31;
        const float* xr = x + (size_t)(row0 + r) * Lc;
        #pragma unroll
        for (int i = 0; i < 4; ++i) {
            const int c4 = 4 * (sc + 32 * i);   // 0..508
            const int g = s0 + c4;
            float4 v;
            v.x = (g + 0 >= 0 && g + 0 < Lc) ? xr[g + 0] : 0.f;
            v.y = (g + 1 >= 0 && g + 1 < Lc) ? xr[g + 1] : 0.f;
            v.z = (g + 2 >= 0 && g + 2 < Lc) ? xr[g + 2] : 0.f;
            v.w = (g + 3 >= 0 && g + 3 < Lc) ? xr[g + 3] : 0.f;
            *reinterpret_cast<float4*>(&lf[buf][r * F32STR + c4]) = v;
        }
    };

    // ---- CONV: wave's own rows, fp32 LDS -> bf16 LDS (dw 0..399) ----
    auto CONV = [&](int buf) {
        #pragma unroll
        for (int rr = 0; rr < 2; ++rr) {
            const int r = 2 * wv + rr;
            {
                float4 v = *reinterpret_cast<const float4*>(&lf[buf][r * F32STR + 4 * lane]);
                __hip_bfloat162 p0 = __float22bfloat162_rn(make_float2(v.x, v.y));
                __hip_bfloat162 p1 = __float22bfloat162_rn(make_float2(v.z, v.w));
                ushort2 u0, u1;
                __builtin_memcpy(&u0, &p0, 4);
                __builtin_memcpy(&u1, &p1, 4);
                ushort4 h; h.x = u0.x; h.y = u0.y; h.z = u1.x; h.w = u1.y;
                *reinterpret_cast<ushort4*>(&lb[r * BFSTR + 4 * lane]) = h;
            }
            if (lane < 36) {
                float4 v = *reinterpret_cast<const float4*>(&lf[buf][r * F32STR + 256 + 4 * lane]);
                __hip_bfloat162 p0 = __float22bfloat162_rn(make_float2(v.x, v.y));
                __hip_bfloat162 p1 = __float22bfloat162_rn(make_float2(v.z, v.w));
                ushort2 u0, u1;
                __builtin_memcpy(&u0, &p0, 4);
                __builtin_memcpy(&u1, &p1, 4);
                ushort4 h; h.x = u0.x; h.y = u0.y; h.z = u1.x; h.w = u1.y;
                *reinterpret_cast<ushort4*>(&lb[r * BFSTR + 256 + 4 * lane]) = h;
            }
        }
    };

    // ---- COMPUTE: 2 tiles/wave, 5 ds_read_b128 + 10 MFMA each ----
    auto COMPUTE = [&](int pc) {
        const int P0 = pc * MLEN;
        #pragma unroll
        for (int jj = 0; jj < 2; ++jj) {
            const int j = wv * 2 + jj;          // tile 0..15
            const unsigned short* lp = &lb[BFSTR * fn + 16 * j + 8 * fh];
            floatx4 cr = {0.f, 0.f, 0.f, 0.f};
            floatx4 cim = {0.f, 0.f, 0.f, 0.f};
            #pragma unroll
            for (int d = 0; d < 5; ++d) {
                short8 b = *reinterpret_cast<const short8*>(lp + 32 * d);
                cr  = __builtin_amdgcn_mfma_f32_16x16x32_bf16(ar[d], b, cr, 0, 0, 0);
                cim = __builtin_amdgcn_mfma_f32_16x16x32_bf16(ai[d], b, cim, 0, 0, 0);
            }
            const size_t obase = (size_t)(row0 + fn) * Lc + P0 + 16 * j + 4 * fh;
            if (!interleaved) {
                float4 o;
                o.x = scv * cr[0] - ssv * cim[0];
                o.y = scv * cr[1] - ssv * cim[1];
                o.z = scv * cr[2] - ssv * cim[2];
                o.w = scv * cr[3] - ssv * cim[3];
                *reinterpret_cast<float4*>(out + obase) = o;
            } else {
                float2* o2 = reinterpret_cast<float2*>(out) + obase;
                #pragma unroll
                for (int r = 0; r < 4; ++r) {
                    o2[r] = make_float2(scv * cr[r] - ssv * cim[r],
                                        -scv * cim[r] - ssv * cr[r]);
                }
            }
        }
    };

    // ---- prologue: prime chunks 0 and 1 ----
    const int pc0 = bx * NCH;
    if (pc0 == 0) EDGE(0, 0); else DMA(pc0, 0);
    DMA(pc0 + 1, 1);

    // ---- main loop: counted vmcnt, raw barriers (no vmcnt drain) ----
    #pragma unroll 1
    for (int c = 0; c < NCH; ++c) {
        const int pc  = pc0 + c;
        const int buf = c & 1;

        // wait for chunk c's DMA: younger ops = stores + DMA(c+1) (counted)
        if (c == 0)            asm volatile("s_waitcnt vmcnt(4)" ::: "memory");
        else if (c == 1)       asm volatile("s_waitcnt vmcnt(6)" ::: "memory");
        else if (c == NCH - 1) asm volatile("s_waitcnt vmcnt(4)" ::: "memory");
        else                   asm volatile("s_waitcnt vmcnt(8)" ::: "memory");
        __builtin_amdgcn_sched_barrier(0);

        CONV(buf);
        asm volatile("s_waitcnt lgkmcnt(0)" ::: "memory");
        __builtin_amdgcn_sched_barrier(0);

        if (c + 2 < NCH) {
            const int npc = pc + 2;
            if (npc == 127) EDGE(npc, buf); else DMA(npc, buf);
        }
        __builtin_amdgcn_s_barrier();      // all waves' bf16 rows ready
        __builtin_amdgcn_sched_barrier(0);

        COMPUTE(pc);
        asm volatile("s_waitcnt lgkmcnt(0)" ::: "memory");
        __builtin_amdgcn_sched_barrier(0);
        __builtin_amdgcn_s_barrier();      // bf16 buffer free for next CONV
        __builtin_amdgcn_sched_barrier(0);
    }
}

extern "C" void kernel_launch(void* const* d_in, const int* in_sizes, int n_in,
                              void* d_out, int out_size, void* d_ws, size_t ws_size,
                              hipStream_t stream) {
    const float* x  = (const float*)d_in[0];
    const float* wm = (const float*)d_in[1];
    const float* wa = (const float*)d_in[2];
    const float* kr = (const float*)d_in[3];
    const float* ki = (const float*)d_in[4];
    float* out = (float*)d_out;
    float* ws  = (float*)d_ws;

    const int C = in_sizes[1];  // 128
    const long long N = (long long)Bc * Cc * Lc;
    const int interleaved = (out_size == 2 * N) ? 1 : 0;

    hipLaunchKernelGGL(scale_kernel, dim3(1), dim3(C), 0, stream,
                       wm, wa, ws, C, (float)Bc);

    dim3 grid(Lc / (MLEN * NCH), (Bc * Cc) / ROWS);   // 8 x 64 = 512 blocks
    hipLaunchKernelGGL(mf_kernel, grid, dim3(THREADS), 0, stream,
                       x, kr, ki, ws, out, interleaved);
}

// Round 15
// 70.468 us; speedup vs baseline: 2.1863x; 1.0607x over previous
//
#include <hip/hip_runtime.h>
#include <hip/hip_bf16.h>
#include <math.h>

// OptimizeSNR R15: wave-autonomous Toeplitz-swap MFMA. ZERO barriers.
//   out[t0+16m+n] = sum_p A[m,p]*B[p,n],  A[m,p]=x[t0-64+16m+p] (x-window,
//   wave-private LDS), B[p,n]=k[p-n] (k-Toeplitz, VGPRs).
//   One wave = one row segment; depth-2 counted-vmcnt DMA pipeline.
constexpr int Bc = 8, Cc = 128, Lc = 32768, Kc = 129, PAD = 64;

constexpr int MLEN = 256;            // outputs per chunk (one 16x16 tile)
constexpr int T    = 16;             // chunks per wave
constexpr int NSEG = Lc / (MLEN * T);// 8 segments per row
constexpr int WPB  = 4;              // waves per block
constexpr int THREADS = 64 * WPB;    // 256
constexpr int LASTCW  = Lc / MLEN - 1; // 127

typedef __attribute__((ext_vector_type(8))) short short8;
typedef __attribute__((ext_vector_type(4))) float floatx4;

#define WAITVM(N) do { asm volatile("s_waitcnt vmcnt(" #N ")" ::: "memory"); \
                       __builtin_amdgcn_sched_barrier(0); } while (0)
#define WAITLG()  do { asm volatile("s_waitcnt lgkmcnt(0)" ::: "memory"); \
                       __builtin_amdgcn_sched_barrier(0); } while (0)

__device__ __forceinline__ unsigned short f2bf(float f) {
    return __builtin_bit_cast(unsigned short, __float2bfloat16(f));
}

__device__ __forceinline__ short8 cvt8(const float4& a, const float4& b) {
    __hip_bfloat162 p0 = __float22bfloat162_rn(make_float2(a.x, a.y));
    __hip_bfloat162 p1 = __float22bfloat162_rn(make_float2(a.z, a.w));
    __hip_bfloat162 p2 = __float22bfloat162_rn(make_float2(b.x, b.y));
    __hip_bfloat162 p3 = __float22bfloat162_rn(make_float2(b.z, b.w));
    ushort2 u0, u1, u2, u3;
    __builtin_memcpy(&u0, &p0, 4);
    __builtin_memcpy(&u1, &p1, 4);
    __builtin_memcpy(&u2, &p2, 4);
    __builtin_memcpy(&u3, &p3, 4);
    short8 r;
    r[0] = (short)u0.x; r[1] = (short)u0.y;
    r[2] = (short)u1.x; r[3] = (short)u1.y;
    r[4] = (short)u2.x; r[5] = (short)u2.y;
    r[6] = (short)u3.x; r[7] = (short)u3.y;
    return r;
}

__device__ __forceinline__ void gload_lds16(const float* g, void* l) {
    auto gp = (const __attribute__((address_space(1))) void*)g;
    auto lp = (__attribute__((address_space(3))) void*)l;
    __builtin_amdgcn_global_load_lds(gp, lp, 16, 0, 0);
}

// Per-channel complex scale: sc = nm*cos(atan(a)), ss = nm*sin(atan(a))
__global__ void scale_kernel(const float* __restrict__ wm,
                             const float* __restrict__ wa,
                             float* __restrict__ ws, int C, float batchf) {
    int c = threadIdx.x;
    if (c >= C) return;
    float m = -1e30f;
    for (int i = 0; i < C; ++i) m = fmaxf(m, wm[i]);
    float s = 0.f;
    for (int i = 0; i < C; ++i) s += expf(wm[i] - m);
    float nm = batchf * expf(wm[c] - m) / s;
    float a = wa[c];
    float inv = rsqrtf(1.f + a * a);
    ws[2 * c]     = nm * inv;       // sc
    ws[2 * c + 1] = nm * a * inv;   // ss
}

__global__ __launch_bounds__(THREADS, 5)
void mf_kernel(const float* __restrict__ x,
               const float* __restrict__ kr,
               const float* __restrict__ ki,
               const float* __restrict__ sc_ss,
               float* __restrict__ out, int interleaved) {
    __shared__ __align__(16) float          lf[WPB][2][512];  // 16 KB fp32 stage
    __shared__ __align__(16) unsigned short lb[WPB][2][512];  // 8 KB bf16 window

    const int seg = blockIdx.x;            // 8 segments
    const int rg  = blockIdx.y;            // 256 row groups (4 rows)
    const int tid = threadIdx.x;
    const int lane= tid & 63;
    const int wv  = tid >> 6;              // wave 0..3
    const int fh  = lane >> 4;             // 0..3
    const int fn  = lane & 15;             // 0..15

    const int row = rg * WPB + wv;         // this wave's row (0..1023)
    const int cw0 = seg * T;               // first chunk

    // ---- B fragments (k-Toeplitz): B_d[kl][n] = k[32d + kl - n]; lane: n=fn, kl=8*fh+e
    short8 br[5], bi[5];
    #pragma unroll
    for (int d = 0; d < 5; ++d) {
        #pragma unroll
        for (int e = 0; e < 8; ++e) {
            int idx = 32 * d + 8 * fh + e - fn;
            bool ok = (idx >= 0) && (idx < Kc);
            br[d][e] = (short)f2bf(ok ? kr[idx] : 0.f);
            bi[d][e] = (short)f2bf(ok ? ki[idx] : 0.f);
        }
    }

    const int ch = row & (Cc - 1);
    const float scv = sc_ss[2 * ch];
    const float ssv = sc_ss[2 * ch + 1];

    const float* __restrict__ xrow = x + (size_t)row * Lc;

    auto DMA = [&](int cw, int buf) {   // interior chunks only
        const float* g = xrow + (cw * MLEN - PAD) + 4 * lane;
        char* l = (char*)&lf[wv][buf][0];
        gload_lds16(g, l);
        gload_lds16(g + 256, l + 1024);
    };

    auto TILE = [&](int cw, int buf) {  // window in lb[wv][buf] -> 256 outputs
        const unsigned short* ab = &lb[wv][buf][0];
        short8 a[5];
        #pragma unroll
        for (int d = 0; d < 5; ++d)
            a[d] = *reinterpret_cast<const short8*>(ab + 16 * fn + 8 * fh + 32 * d);
        WAITLG();
        floatx4 cr = {0.f, 0.f, 0.f, 0.f};
        floatx4 ci = {0.f, 0.f, 0.f, 0.f};
        #pragma unroll
        for (int d = 0; d < 5; ++d) {
            cr = __builtin_amdgcn_mfma_f32_16x16x32_bf16(a[d], br[d], cr, 0, 0, 0);
            ci = __builtin_amdgcn_mfma_f32_16x16x32_bf16(a[d], bi[d], ci, 0, 0, 0);
        }
        // D[m=4*fh+r][n=fn]; output pos = cw*256 + 16m + n
        if (!interleaved) {
            float* op = out + (size_t)row * Lc + cw * MLEN + 64 * fh + fn;
            #pragma unroll
            for (int r = 0; r < 4; ++r)
                op[16 * r] = scv * cr[r] - ssv * ci[r];
        } else {
            float2* op = reinterpret_cast<float2*>(out) +
                         ((size_t)row * Lc + cw * MLEN + 64 * fh + fn);
            #pragma unroll
            for (int r = 0; r < 4; ++r)
                op[16 * r] = make_float2(scv * cr[r] - ssv * ci[r],
                                         -scv * ci[r] - ssv * cr[r]);
        }
    };

    // ---- prologue: prime chunks cw0, cw0+1 ----
    if (cw0 != 0) DMA(cw0, 0);             // cw0==0 => edge, handled in loop
    DMA(cw0 + 1, 1);

    #pragma unroll
    for (int c = 0; c < T; ++c) {
        const int cw  = cw0 + c;
        const int buf = c & 1;
        const bool edge = (cw == 0) || (cw == LASTCW);

        if (edge) {
            // guarded reg staging straight into bf16 window
            const int g0 = cw * MLEN - PAD + 8 * lane;
            float vv[8];
            #pragma unroll
            for (int jj = 0; jj < 8; ++jj) {
                const int g = g0 + jj;
                vv[jj] = (g >= 0 && g < Lc) ? xrow[g] : 0.f;
            }
            if (c + 2 < T) DMA(cw + 2, buf);
            float4 va = make_float4(vv[0], vv[1], vv[2], vv[3]);
            float4 vb = make_float4(vv[4], vv[5], vv[6], vv[7]);
            short8 h = cvt8(va, vb);
            *reinterpret_cast<short8*>(&lb[wv][buf][8 * lane]) = h;
            WAITLG();
            TILE(cw, buf);
        } else {
            // wait this chunk's DMA (exact counted; conservative at tail)
            if (c == 0)          WAITVM(2);
            else if (c == 1)     WAITVM(6);
            else if (c >= T - 2) WAITVM(8);
            else                 WAITVM(10);

            const floatx4* lp = reinterpret_cast<const floatx4*>(&lf[wv][buf][0]);
            floatx4 va4 = lp[2 * lane];
            floatx4 vb4 = lp[2 * lane + 1];
            WAITLG();                       // fp32 in regs -> buffer reusable
            if (c + 2 < T && (cw + 2) != LASTCW) DMA(cw + 2, buf);
            float4 va = make_float4(va4[0], va4[1], va4[2], va4[3]);
            float4 vb = make_float4(vb4[0], vb4[1], vb4[2], vb4[3]);
            short8 h = cvt8(va, vb);
            *reinterpret_cast<short8*>(&lb[wv][buf][8 * lane]) = h;
            WAITLG();                       // bf16 window visible wave-wide
            TILE(cw, buf);
        }
    }
}

extern "C" void kernel_launch(void* const* d_in, const int* in_sizes, int n_in,
                              void* d_out, int out_size, void* d_ws, size_t ws_size,
                              hipStream_t stream) {
    const float* x  = (const float*)d_in[0];
    const float* wm = (const float*)d_in[1];
    const float* wa = (const float*)d_in[2];
    const float* kr = (const float*)d_in[3];
    const float* ki = (const float*)d_in[4];
    float* out = (float*)d_out;
    float* ws  = (float*)d_ws;

    const int C = in_sizes[1];  // 128
    const long long N = (long long)Bc * Cc * Lc;
    const int interleaved = (out_size == 2 * N) ? 1 : 0;

    hipLaunchKernelGGL(scale_kernel, dim3(1), dim3(C), 0, stream,
                       wm, wa, ws, C, (float)Bc);

    dim3 grid(NSEG, (Bc * Cc) / WPB);   // 8 x 256 = 2048 blocks
    hipLaunchKernelGGL(mf_kernel, grid, dim3(THREADS), 0, stream,
                       x, kr, ki, ws, out, interleaved);
}